// Round 5
// baseline (346.346 us; speedup 1.0000x reference)
//
#include <hip/hip_runtime.h>
#include <math.h>

typedef __bf16 bf16_t;
typedef __bf16 bf16x4 __attribute__((ext_vector_type(4)));
typedef __bf16 bf16x8 __attribute__((ext_vector_type(8)));
typedef float  f32x4  __attribute__((ext_vector_type(4)));

#define FNUM 256
#define KPAD 608          // 600 padded to 608 (19 K-steps of 32)
#define NKS  19

// ---------------- W prep: f32 [256][600] -> swizzled bf16 MFMA-fragment tiles ----------------
// Per branch: tiles (ks, ft), tile = 64 lanes x 8 bf16 contiguous (1024 B).
//   lane l -> f = ft*16 + (l&15), k = ks*32 + (l>>4)*8 + e; zero for k >= 600.
__global__ __launch_bounds__(256)
void prep_w_swz(const float* __restrict__ w0, const float* __restrict__ w1,
                const float* __restrict__ w2, const float* __restrict__ w3,
                const float* __restrict__ w4, bf16_t* __restrict__ wp) {
    int tg = blockIdx.x * 4 + (threadIdx.x >> 6);    // global tile id, 5*19*16 = 1520
    if (tg >= 1520) return;
    int l  = threadIdx.x & 63;
    int br = tg / 304;
    int rem = tg % 304;
    int ks = rem / 16, ft = rem % 16;
    const float* src;
    switch (br) {
        case 0: src = w0; break;
        case 1: src = w1; break;
        case 2: src = w2; break;
        case 3: src = w3; break;
        default: src = w4; break;
    }
    int f = ft * 16 + (l & 15);
    int k0 = ks * 32 + (l >> 4) * 8;
    bf16x8 v;
#pragma unroll
    for (int e = 0; e < 8; e++) {
        int k = k0 + e;
        v[e] = (k < 600) ? (bf16_t)src[(size_t)f * 600 + k] : (bf16_t)0.f;
    }
    *(bf16x8*)(wp + (size_t)br * FNUM * KPAD + ((size_t)(ks * 16 + ft) * 512 + (size_t)l * 8)) = v;
}

// ---------------- conv over a FULL batch: one block per batch ----------------
// 512 threads = 8 waves, 4M x 2N: wave wm=w&3 owns f [wm*64, wm*64+64); wn=w>>2 owns
// t-fragments [0,NF0) or [NF0, NF0+NF1). Whole X (L rows) staged once in LDS as bf16;
// K=608 loop streams swizzled W tiles from L2 with depth-1 prefetch. relu+bias+t-mask,
// t-sum, cross-wave combine, in-block unit-normalize -> out[batch][256].
// Doc rider: blocks >= nMain use X2/W2/bias2 and write out2[256].
template<int NF0, int NF1>
__global__ __launch_bounds__(512, 2)
void conv_full(const float* __restrict__ X, const bf16_t* __restrict__ Wswz,
               const float* __restrict__ bias, float* __restrict__ out,
               int L, int T,
               const float* __restrict__ X2, const bf16_t* __restrict__ W2,
               const float* __restrict__ bias2, float* __restrict__ out2, int nMain) {
    constexpr int NFT   = NF0 + NF1;
    constexpr int NROWS = NFT * 16 + 1;
    __shared__ bf16_t Xlds[NROWS * 300 + 8];
    __shared__ float  feat2[512];
    __shared__ float  red[8];

    const int tid = threadIdx.x;
    const int l   = tid & 63;
    const int w   = tid >> 6;
    const int wm  = w & 3;
    const int wn  = w >> 2;
    const int g   = l >> 4;
    const int l15 = l & 15;

    const bool rider = ((int)blockIdx.x >= nMain);
    const float*  Xb = rider ? X2 : X + (size_t)blockIdx.x * L * 300;
    const bf16_t* Wb = rider ? W2 : Wswz;
    const float*  bp = rider ? bias2 : bias;

    // ---- stage all L rows of X as bf16 (contiguous; im2col via row overlap), zero-pad ----
    {
        const int vr  = (L < NROWS) ? L : NROWS;
        const int nF4 = vr * 75;
        for (int v = tid; v < nF4; v += 512) {
            float4 fv = *(const float4*)(Xb + (size_t)v * 4);
            bf16x4 hv = { (bf16_t)fv.x, (bf16_t)fv.y, (bf16_t)fv.z, (bf16_t)fv.w };
            *(bf16x4*)(Xlds + v * 4) = hv;
        }
        bf16x4 z4 = { (bf16_t)0.f, (bf16_t)0.f, (bf16_t)0.f, (bf16_t)0.f };
        for (int v = nF4 + tid; v < NROWS * 75; v += 512)
            *(bf16x4*)(Xlds + v * 4) = z4;
        if (tid < 4) ((unsigned int*)(Xlds + NROWS * 300))[tid] = 0u;   // 16B guard (k->607 overrun)
    }

    const int nf      = wn ? NF1 : NF0;        // wave-uniform fragment count
    const int tbase16 = wn ? NF0 * 16 : 0;
    constexpr int NFMAX = NF0;                 // NF0 >= NF1 by construction

    // A-tile pointer: wave wm's tiles at K-step ks: wa + ks*16*512 + i*512
    const bf16_t* wa = Wb + ((size_t)(wm * 4) * 512 + (size_t)l * 8);

    int boff[NFMAX];
#pragma unroll
    for (int j = 0; j < NFMAX; j++)
        boff[j] = (tbase16 + j * 16 + l15) * 300 + g * 8;

    bf16x8 aCur[4], aNxt[4];
#pragma unroll
    for (int i = 0; i < 4; i++) aCur[i] = *(const bf16x8*)(wa + i * 512);

    __syncthreads();

    f32x4 acc[4][NFMAX];
#pragma unroll
    for (int i = 0; i < 4; i++)
#pragma unroll
        for (int j = 0; j < NFMAX; j++)
            acc[i][j] = (f32x4){0.f, 0.f, 0.f, 0.f};

    for (int ks = 0; ks < NKS; ++ks) {
        if (ks + 1 < NKS) {
            const bf16_t* wp_n = wa + (size_t)(ks + 1) * 16 * 512;
#pragma unroll
            for (int i = 0; i < 4; i++) aNxt[i] = *(const bf16x8*)(wp_n + i * 512);
        }
        const int k0 = ks * 32;
        bf16x8 bb[NFMAX];
#pragma unroll
        for (int j = 0; j < NFMAX; j++) {
            if (j < nf) {
                bf16x4 lo = *(const bf16x4*)(Xlds + boff[j] + k0);
                bf16x4 hi = *(const bf16x4*)(Xlds + boff[j] + k0 + 4);
                bb[j] = __builtin_shufflevector(lo, hi, 0, 1, 2, 3, 4, 5, 6, 7);
            }
        }
#pragma unroll
        for (int i = 0; i < 4; i++)
#pragma unroll
            for (int j = 0; j < NFMAX; j++)
                if (j < nf)
                    acc[i][j] = __builtin_amdgcn_mfma_f32_16x16x32_bf16(aCur[i], bb[j], acc[i][j], 0, 0, 0);
#pragma unroll
        for (int i = 0; i < 4; i++) aCur[i] = aNxt[i];
    }

    // ---- epilogue: relu(C + bias), mask t<T, reduce over t; cross-wn via feat2 ----
#pragma unroll
    for (int i = 0; i < 4; i++) {
#pragma unroll
        for (int r = 0; r < 4; r++) {
            const int row = wm * 64 + i * 16 + g * 4 + r;
            const float bi = bp[row];
            float s = 0.f;
#pragma unroll
            for (int j = 0; j < NFMAX; j++) {
                if (j < nf) {
                    int t = tbase16 + j * 16 + l15;
                    float v = acc[i][j][r] + bi;
                    v = fmaxf(v, 0.f);
                    s += (t < T) ? v : 0.f;
                }
            }
            s += __shfl_xor(s, 1);
            s += __shfl_xor(s, 2);
            s += __shfl_xor(s, 4);
            s += __shfl_xor(s, 8);
            if (l15 == 0) feat2[wn * 256 + row] = s;
        }
    }
    __syncthreads();

    // combine wn halves + unit-normalize
    float v = 0.f, sq = 0.f;
    if (tid < 256) { v = feat2[tid] + feat2[256 + tid]; sq = v * v; }
    sq += __shfl_xor(sq, 1);
    sq += __shfl_xor(sq, 2);
    sq += __shfl_xor(sq, 4);
    sq += __shfl_xor(sq, 8);
    sq += __shfl_xor(sq, 16);
    sq += __shfl_xor(sq, 32);
    if (l == 0) red[w] = sq;
    __syncthreads();
    float tot = red[0] + red[1] + red[2] + red[3];
    if (tid < 256) {
        float* outp = rider ? out2 : (out + (size_t)blockIdx.x * 256);
        outp[tid] = v / sqrtf(tot);
    }
}

// ---------------- dt/db: dot normalized doc features with net/neb rows ----------------
__global__ __launch_bounds__(256)
void dt_db_kernel(const float* __restrict__ nmd, const float* __restrict__ net,
                  const float* __restrict__ neb, float* __restrict__ dt,
                  float* __restrict__ db) {
    __shared__ float md[256];
    int tid = threadIdx.x;
    md[tid] = nmd[tid];
    __syncthreads();
    int n = blockIdx.x * 256 + tid;
    const float4* tp = (const float4*)(net + (size_t)n * 256);
    const float4* bp = (const float4*)(neb + (size_t)n * 256);
    float dT = 0.f, dB = 0.f;
    for (int i = 0; i < 64; i++) {
        float4 mm = *(const float4*)(md + i * 4);
        float4 tv = tp[i], bv = bp[i];
        dT += mm.x * tv.x + mm.y * tv.y + mm.z * tv.z + mm.w * tv.w;
        dB += mm.x * bv.x + mm.y * bv.y + mm.z * bv.z + mm.w * bv.w;
    }
    dt[n] = dT;
    db[n] = dB;
}

// ---------------- cosines + linear + masked softmax (one block per mention row) ----------------
__global__ __launch_bounds__(256)
void pair_kernel(const float* __restrict__ nms, const float* __restrict__ nmc,
                 const float* __restrict__ net, const float* __restrict__ neb,
                 const float* __restrict__ dt, const float* __restrict__ db,
                 const float* __restrict__ wl, const float* __restrict__ bl,
                 const int* __restrict__ me, float* __restrict__ out) {
    __shared__ float sA[256], sB[256], red[4];
    int tid = threadIdx.x, m = blockIdx.x;
    sA[tid] = nms[(size_t)m * 256 + tid];
    sB[tid] = nmc[(size_t)m * 256 + tid];
    __syncthreads();
    float w0 = wl[0], w1 = wl[1], w2 = wl[2], w3 = wl[3], w4 = wl[4], w5 = wl[5], b = bl[0];

    float dst[4], dct[4], dsb[4], dcb[4];
#pragma unroll
    for (int q = 0; q < 4; q++) { dst[q] = 0.f; dct[q] = 0.f; dsb[q] = 0.f; dcb[q] = 0.f; }

    for (int i = 0; i < 64; i++) {
        float4 a = *(const float4*)(sA + i * 4);
        float4 c = *(const float4*)(sB + i * 4);
#pragma unroll
        for (int q = 0; q < 4; q++) {
            int n = q * 256 + tid;
            float4 tv = *(const float4*)(net + (size_t)n * 256 + i * 4);
            float4 bv = *(const float4*)(neb + (size_t)n * 256 + i * 4);
            dst[q] += a.x * tv.x + a.y * tv.y + a.z * tv.z + a.w * tv.w;
            dct[q] += c.x * tv.x + c.y * tv.y + c.z * tv.z + c.w * tv.w;
            dsb[q] += a.x * bv.x + a.y * bv.y + a.z * bv.z + a.w * bv.w;
            dcb[q] += c.x * bv.x + c.y * bv.y + c.z * bv.z + c.w * bv.w;
        }
    }

    float sc[4], ev[4];
    float esum = 0.f;
#pragma unroll
    for (int q = 0; q < 4; q++) {
        int n = q * 256 + tid;
        float msk = (float)me[(size_t)m * 1024 + n];
        float f_st = dst[q] * 0.5f + 0.5f;
        float f_dt = dt[n] * 0.5f + 0.5f;
        float f_ct = dct[q] * 0.5f + 0.5f;
        float f_sb = dsb[q] * 0.5f + 0.5f;
        float f_db = db[n] * 0.5f + 0.5f;
        float f_cb = dcb[q] * 0.5f + 0.5f;
        float s = f_st * w0 + f_dt * w1 + f_ct * w2 + f_sb * w3 + f_db * w4 + f_cb * w5 + b;
        s = (msk != 0.f) ? s : 0.f;
        sc[q] = s;
        ev[q] = (msk != 0.f) ? expf(s / 0.1f) : 0.f;
        esum += ev[q];
    }
    esum += __shfl_xor(esum, 1);
    esum += __shfl_xor(esum, 2);
    esum += __shfl_xor(esum, 4);
    esum += __shfl_xor(esum, 8);
    esum += __shfl_xor(esum, 16);
    esum += __shfl_xor(esum, 32);
    if ((tid & 63) == 0) red[tid >> 6] = esum;
    __syncthreads();
    float tot = red[0] + red[1] + red[2] + red[3];
#pragma unroll
    for (int q = 0; q < 4; q++) {
        int n = q * 256 + tid;
        out[(size_t)m * 1024 + n] = sc[q];
        out[256 * 1024 + (size_t)m * 1024 + n] = ev[q] / tot;
    }
}

extern "C" void kernel_launch(void* const* d_in, const int* in_sizes, int n_in,
                              void* d_out, int out_size, void* d_ws, size_t ws_size,
                              hipStream_t stream) {
    const float* mention = (const float*)d_in[0];
    const float* context = (const float*)d_in[1];
    const float* doc     = (const float*)d_in[2];
    const float* title   = (const float*)d_in[3];
    const float* body    = (const float*)d_in[4];
    const float* W_ms = (const float*)d_in[5];  const float* b_ms = (const float*)d_in[6];
    const float* W_mc = (const float*)d_in[7];  const float* b_mc = (const float*)d_in[8];
    const float* W_md = (const float*)d_in[9];  const float* b_md = (const float*)d_in[10];
    const float* W_et = (const float*)d_in[11]; const float* b_et = (const float*)d_in[12];
    const float* W_eb = (const float*)d_in[13]; const float* b_eb = (const float*)d_in[14];
    const float* w_local = (const float*)d_in[15];
    const float* b_local = (const float*)d_in[16];
    const int*   me      = (const int*)d_in[17];
    float* out = (float*)d_out;

    char* ws = (char*)d_ws;
    bf16_t* Wp = (bf16_t*)ws;
    size_t off = (size_t)5 * FNUM * KPAD * 2;             // W bf16 swizzled: 1,556,480 B
    float* nms = (float*)(ws + off); off += 256 * 256 * 4;
    float* nmc = (float*)(ws + off); off += 256 * 256 * 4;
    float* net = (float*)(ws + off); off += 1024 * 256 * 4;
    float* neb = (float*)(ws + off); off += 1024 * 256 * 4;
    float* nmd = (float*)(ws + off); off += 256 * 4;
    float* dt  = (float*)(ws + off); off += 1024 * 4;
    float* db  = (float*)(ws + off); off += 1024 * 4;

    const bf16_t* Wms = Wp + (size_t)0 * FNUM * KPAD;
    const bf16_t* Wmc = Wp + (size_t)1 * FNUM * KPAD;
    const bf16_t* Wmd = Wp + (size_t)2 * FNUM * KPAD;
    const bf16_t* Wet = Wp + (size_t)3 * FNUM * KPAD;
    const bf16_t* Web = Wp + (size_t)4 * FNUM * KPAD;

    prep_w_swz<<<380, 256, 0, stream>>>(W_ms, W_mc, W_md, W_et, W_eb, Wp);

    // body: one block per batch, whole X in LDS; doc rides as block 1024 -> nmd
    conv_full<7, 6><<<1025, 512, 0, stream>>>(body, Web, b_eb, neb, 200, 199,
                                              doc, Wmd, b_md, nmd, 1024);
    // small branches (2 fragments cover T)
    conv_full<1, 1><<<1024, 512, 0, stream>>>(title,   Wet, b_et, net, 20, 19,
                                              nullptr, nullptr, nullptr, nullptr, 1 << 30);
    conv_full<1, 1><<<256,  512, 0, stream>>>(context, Wmc, b_mc, nmc, 20, 19,
                                              nullptr, nullptr, nullptr, nullptr, 1 << 30);
    conv_full<1, 1><<<256,  512, 0, stream>>>(mention, Wms, b_ms, nms, 10, 9,
                                              nullptr, nullptr, nullptr, nullptr, 1 << 30);

    dt_db_kernel<<<4, 256, 0, stream>>>(nmd, net, neb, dt, db);
    pair_kernel<<<256, 256, 0, stream>>>(nms, nmc, net, neb, dt, db, w_local, b_local, me, out);
}